// Round 10
// baseline (137.390 us; speedup 1.0000x reference)
//
#include <hip/hip_runtime.h>
#include <hip/hip_bf16.h>

#define N_ATOMS 512
#define CDIM 64
#define NSIG 16384
#define KS 4
#define NBINS 33
#define NS_BLK 4    // signals per fused block (4 waves; wave = 128 atoms in GEMM, 1 signal in OMP)

// ws layout (floats): [0,32768) Dn[c][n] ; [32768,65536) DnT[n][c] ;
// [65536,327680) G[n][n]
#define WS_DN   0
#define WS_DNT  32768
#define WS_G    65536
#define LOSS_IDX (NSIG * CDIM)

// k_normalize also zero-inits the loss slot for the fused kernel's atomics.
__global__ void k_normalize(const float* __restrict__ dict,
                            float* __restrict__ Dn, float* __restrict__ DnT,
                            float* __restrict__ out) {
    const int n = blockIdx.x;    // atom/column
    const int c = threadIdx.x;   // channel/row (64 threads = 1 wave)
    float v = dict[c * N_ATOMS + n];
    float sq = v * v;
    #pragma unroll
    for (int off = 32; off > 0; off >>= 1) sq += __shfl_down(sq, off);
    sq = __shfl(sq, 0);
    float m = fmaxf(sqrtf(sq), 1e-10f);
    float r = v / m;             // division to match reference exactly
    Dn[c * N_ATOMS + n] = r;
    DnT[n * CDIM + c]  = r;
    if (n == 0 && c == 0) out[LOSS_IDX] = 0.f;
}

__global__ void k_gram(const float* __restrict__ Dn, float* __restrict__ G) {
    __shared__ float sc[CDIM];
    const int i = blockIdx.x;
    const int t = threadIdx.x;
    if (t < CDIM) sc[t] = Dn[t * N_ATOMS + i];
    __syncthreads();
    for (int j = t; j < N_ATOMS; j += 256) {
        float a = 0.f;
        #pragma unroll
        for (int c = 0; c < CDIM; c++) a = fmaf(sc[c], Dn[c * N_ATOMS + j], a);
        G[i * N_ATOMS + j] = a;
    }
}

// 8-way select, VALUE-passed (pointer-escape of register arrays sends them
// to scratch — round-4 lesson). e wave-uniform; 7-cndmask tree.
__device__ __forceinline__ float sel8v(float f0, float f1, float f2, float f3,
                                       float f4, float f5, float f6, float f7,
                                       int e) {
    float x0 = (e & 1) ? f1 : f0;
    float x1 = (e & 1) ? f3 : f2;
    float x2 = (e & 1) ? f5 : f4;
    float x3 = (e & 1) ? f7 : f6;
    float y0 = (e & 2) ? x1 : x0;
    float y1 = (e & 2) ? x3 : x2;
    return (e & 4) ? y1 : y0;
}
#define SEL8(arr, e) sel8v(arr[0], arr[1], arr[2], arr[3], \
                           arr[4], arr[5], arr[6], arr[7], e)

// DPP max step: v = max(v, v shifted by ctrl). bound_ctrl=1 -> OOB lanes
// contribute +0.0f, safe because all reduced values are >= 0. Pure VALU
// (~4 cy) vs ds_bpermute (~40-120 cy) per level.
#define DPPMAX(v, ctrl)                                                     \
    v = fmaxf(v, __int_as_float(__builtin_amdgcn_update_dpp(                \
            0, __float_as_int(v), (ctrl), 0xf, 0xf, true)))

// readlane broadcast of a float from a wave-uniform lane (replaces
// __shfl with uniform src: v_readlane_b32 instead of ds_bpermute).
__device__ __forceinline__ float rdlane_f(float v, int lane) {
    return __int_as_float(__builtin_amdgcn_readlane(__float_as_int(v), lane));
}

// OMP body v15 = v11 with the lane-local argmax restructured as a left-biased
// tournament tree: critical path ~9 ops vs the sequential scan's ~24.
// Left-bias on >= keeps the FIRST maximal element -> identical lowest-index
// tie-break as the scan (including the degenerate all-zero case: both pick
// j=0). Wave reduce (DPP), winner pick (ballot+ffs lowest lane), register
// G-rows, readlane extractions all unchanged from the verified v11.
// Selection/coeff arithmetic identical -> tokens/zste bit-identical.
__device__ __forceinline__ void omp_body(
    const float hb[8], const float* __restrict__ G, int lane,
    int I[KS], float coef[KS])
{
    float h[8];
    #pragma unroll
    for (int j = 0; j < 8; j++) h[j] = hb[j];

    unsigned sel = 0;
    float L[KS][KS];
    float hsel[KS];
    float inv[KS];
    float r[KS - 1][8];                 // kept G-row fragments (registers)
    L[0][0] = 1.f; inv[0] = 1.f;

    #pragma unroll
    for (int k = 0; k < KS; k++) {
        // lane-local argmax of |where(selected, 0, h)| — tournament tree,
        // left-biased (>=) == first-max == lowest-j tie-break
        float m[8];
        #pragma unroll
        for (int j = 0; j < 8; j++)
            m[j] = (sel & (1u << j)) ? 0.f : fabsf(h[j]);
        float va = (m[0] >= m[1]) ? m[0] : m[1]; int ia = (m[0] >= m[1]) ? 0 : 1;
        float vb = (m[2] >= m[3]) ? m[2] : m[3]; int ib = (m[2] >= m[3]) ? 2 : 3;
        float vc = (m[4] >= m[5]) ? m[4] : m[5]; int ic = (m[4] >= m[5]) ? 4 : 5;
        float vd = (m[6] >= m[7]) ? m[6] : m[7]; int id = (m[6] >= m[7]) ? 6 : 7;
        float ve = (va >= vb) ? va : vb;         int ie = (va >= vb) ? ia : ib;
        float vf = (vc >= vd) ? vc : vd;         int jf = (vc >= vd) ? ic : id;
        float bv = (ve >= vf) ? ve : vf;
        const int bn = lane * 8 + ((ve >= vf) ? ie : jf);
        // wave max in lane 63 via DPP (VALU-speed), then SGPR broadcast
        float wv = bv;
        DPPMAX(wv, 0x111);   // row_shr:1
        DPPMAX(wv, 0x112);   // row_shr:2
        DPPMAX(wv, 0x114);   // row_shr:4
        DPPMAX(wv, 0x118);   // row_shr:8
        DPPMAX(wv, 0x142);   // row_bcast:15
        DPPMAX(wv, 0x143);   // row_bcast:31
        const float wm = rdlane_f(wv, 63);
        const int win = (int)__ffsll(__ballot(bv == wm)) - 1; // lowest lane
        const int idx = __builtin_amdgcn_readlane(bn, win);
        if ((idx >> 3) == lane) sel |= 1u << (idx & 7);
        const int owner = idx >> 3, e = idx & 7;

        if (k < KS - 1) {   // load row I[k]=idx early; latency hides under solves
            const float4* gr = (const float4*)(G + idx * N_ATOMS + lane * 8);
            float4 g0 = gr[0], g1 = gr[1];
            r[k][0] = g0.x; r[k][1] = g0.y; r[k][2] = g0.z; r[k][3] = g0.w;
            r[k][4] = g1.x; r[k][5] = g1.y; r[k][6] = g1.z; r[k][7] = g1.w;
        }

        if (k > 0) {
            float w[KS - 1];
            #pragma unroll
            for (int i2 = 0; i2 < k; i2++) {
                float t = rdlane_f(SEL8(r[i2], e), owner);  // G[I[i2]][idx]
                #pragma unroll
                for (int j2 = 0; j2 < i2; j2++) t -= L[i2][j2] * w[j2];
                w[i2] = t * inv[i2];
            }
            float ssum = 0.f;
            #pragma unroll
            for (int j2 = 0; j2 < k; j2++) ssum += w[j2] * w[j2];
            float corner = sqrtf(fmaxf(1.f - ssum, 1e-12f));
            #pragma unroll
            for (int j2 = 0; j2 < k; j2++) L[k][j2] = w[j2];
            L[k][k] = corner;
            inv[k] = 1.f / corner;
        }
        I[k] = idx;
        hsel[k] = rdlane_f(SEL8(hb, e), owner);   // hbar[idx], same bits

        float y[KS];
        #pragma unroll
        for (int i2 = 0; i2 <= k; i2++) {
            float t = hsel[i2];
            #pragma unroll
            for (int j2 = 0; j2 < i2; j2++) t -= L[i2][j2] * y[j2];
            y[i2] = t * inv[i2];
        }
        #pragma unroll
        for (int i2 = k; i2 >= 0; i2--) {
            float t = y[i2];
            #pragma unroll
            for (int j2 = i2 + 1; j2 <= k; j2++) t -= L[j2][i2] * coef[j2];
            coef[i2] = t * inv[i2];
        }

        if (k < KS - 1) {
            float a[8];
            #pragma unroll
            for (int j = 0; j < 8; j++) a[j] = 0.f;
            #pragma unroll
            for (int m2 = 0; m2 <= k; m2++) {
                float cm = coef[m2];
                #pragma unroll
                for (int j = 0; j < 8; j++) a[j] = fmaf(cm, r[m2][j], a[j]);
            }
            #pragma unroll
            for (int j = 0; j < 8; j++) h[j] = hb[j] - a[j];
        }
    }
}

// Fused v15: 256-thr blocks, NS_BLK=4, 1 signal/wave, grid 4096, (256,4)
// bounds (allocator-friendly — r2 precedent 44 VGPR no-spill; min-waves>=8
// is cursed: twice collapsed to 32 VGPR + spill). 8 blocks/CU, finer
// scheduling granularity + half the barrier scope of r7. GEMM: Xs[k] is one
// b128 (4 signals), Dn float2 (2 atoms/lane) — 64 vmem + 64 lds + 512 fma
// per thread vs r7's 64+128+512. Same k-ascending fmaf -> bit-identical.
__global__ __launch_bounds__(256, 4) void k_fused11(
    const float* __restrict__ z, const float* __restrict__ Dn,
    const float* __restrict__ DnT, const float* __restrict__ G,
    float* __restrict__ out)
{
    __shared__ float Xs[CDIM][NS_BLK];      // [c][s] 1 KB (rows b128-aligned)
    __shared__ float Hs[NS_BLK][516];       // hbar tile 8.25 KB; reused for zste
    __shared__ float tk[NS_BLK][KS];
    __shared__ float lred[NS_BLK];
    const int t = threadIdx.x;
    const int wave = t >> 6, lane = t & 63;
    const int s0 = blockIdx.x * NS_BLK;
    const int b = s0 >> 10;
    const int hw0 = s0 & 1023;

    if (t < CDIM) {   // coalesced z stage: c = t, the block's 4 signals
        float4 v = *(const float4*)(z + (b * CDIM + t) * 1024 + hw0);
        *(float4*)(&Xs[t][0]) = v;
    }
    __syncthreads();

    {   // GEMM: wave owns atoms [wave*128, +128); lane owns 2 atoms.
        // k-ascending fmaf per (signal, atom) — bit-identical to prior rounds.
        const int n0 = wave * 128 + lane * 2;
        float acc[NS_BLK][2];
        #pragma unroll
        for (int q = 0; q < NS_BLK; q++) { acc[q][0] = 0.f; acc[q][1] = 0.f; }
        for (int k = 0; k < CDIM; k++) {
            const float2 d = *(const float2*)(Dn + k * N_ATOMS + n0);
            float4 x = *(const float4*)(&Xs[k][0]);     // one b128: 4 signals
            const float xs[NS_BLK] = {x.x, x.y, x.z, x.w};
            #pragma unroll
            for (int q = 0; q < NS_BLK; q++) {
                acc[q][0] = fmaf(xs[q], d.x, acc[q][0]);
                acc[q][1] = fmaf(xs[q], d.y, acc[q][1]);
            }
        }
        #pragma unroll
        for (int q = 0; q < NS_BLK; q++)
            *(float2*)(&Hs[q][n0]) = make_float2(acc[q][0], acc[q][1]);
    }
    __syncthreads();

    // OMP: one signal per wave (sl = wave). 4 independent chains per block,
    // 8 blocks/CU resident.
    {
        const int sl = wave;
        const float xch = Xs[lane][sl];

        float hb[8];
        *(float4*)(&hb[0]) = *(const float4*)(&Hs[sl][lane * 8]);
        *(float4*)(&hb[4]) = *(const float4*)(&Hs[sl][lane * 8 + 4]);

        int I[KS]; float coef[KS];
        omp_body(hb, G, lane, I, coef);

        int tok[KS]; float cq[KS];
        #pragma unroll
        for (int j = 0; j < KS; j++) {
            float c2 = fminf(fmaxf(coef[j], -2.f), 2.f);
            float bf = (c2 + 2.f) / 4.f * 32.f;
            int bin = (int)rintf(bf);
            bin = bin < 0 ? 0 : (bin > 32 ? 32 : bin);
            cq[j] = -2.f + 0.125f * (float)bin;
            tok[j] = I[j] * NBINS + bin;
        }
        float zq = 0.f;
        #pragma unroll
        for (int j = 0; j < KS; j++)
            zq = fmaf(cq[j], DnT[I[j] * CDIM + lane], zq);

        float diff = zq - xch;
        Hs[sl][lane] = xch + (zq - xch);   // zste overlay (row sl read is done)

        float sq = diff * diff;
        #pragma unroll
        for (int off = 32; off > 0; off >>= 1) sq += __shfl_down(sq, off);
        if (lane == 0) lred[sl] = sq;
        if (lane < KS) tk[sl][lane] = (float)tok[lane];
    }
    __syncthreads();

    if (t < CDIM) {   // coalesced zste write: c = t, the block's 4 signals
        float4 v;
        v.x = Hs[0][t]; v.y = Hs[1][t];
        v.z = Hs[2][t]; v.w = Hs[3][t];
        *(float4*)(out + (b * CDIM + t) * 1024 + hw0) = v;
    }
    if (t < NS_BLK * KS)   // 16 consecutive token floats
        out[NSIG * CDIM + 1 + s0 * KS + t] = tk[t >> 2][t & 3];
    if (t == 0) {          // one pre-scaled atomic per block; 1.25/2^20 exact
        atomicAdd(out + LOSS_IDX,
                  (lred[0] + lred[1] + lred[2] + lred[3]) * (1.25f / 1048576.f));
    }
}

extern "C" void kernel_launch(void* const* d_in, const int* in_sizes, int n_in,
                              void* d_out, int out_size, void* d_ws, size_t ws_size,
                              hipStream_t stream) {
    const float* z    = (const float*)d_in[0];
    const float* dict = (const float*)d_in[1];
    float* out  = (float*)d_out;
    float* w    = (float*)d_ws;
    float* Dn   = w + WS_DN;
    float* DnT  = w + WS_DNT;
    float* G    = w + WS_G;

    hipLaunchKernelGGL(k_normalize, dim3(N_ATOMS), dim3(CDIM), 0, stream,
                       dict, Dn, DnT, out);
    hipLaunchKernelGGL(k_gram,      dim3(N_ATOMS), dim3(256),  0, stream, Dn, G);
    hipLaunchKernelGGL(k_fused11,   dim3(NSIG / NS_BLK), dim3(256), 0, stream,
                       z, Dn, DnT, G, out);
}

// Round 11
// 115.084 us; speedup vs baseline: 1.1938x; 1.1938x over previous
//
#include <hip/hip_runtime.h>
#include <hip/hip_bf16.h>

#define N_ATOMS 512
#define CDIM 64
#define NSIG 16384
#define KS 4
#define NBINS 33
#define NS_BLK 8    // signals per fused block (8 waves; wave = 64 atoms in GEMM, 1 signal in OMP)

// ws layout (floats): [0,32768) Dn[c][n] ; [32768,65536) DnT[n][c] ;
// [65536,327680) G[n][n]
#define WS_DN   0
#define WS_DNT  32768
#define WS_G    65536
#define LOSS_IDX (NSIG * CDIM)

// k_normalize also zero-inits the loss slot for the fused kernel's atomics.
__global__ void k_normalize(const float* __restrict__ dict,
                            float* __restrict__ Dn, float* __restrict__ DnT,
                            float* __restrict__ out) {
    const int n = blockIdx.x;    // atom/column
    const int c = threadIdx.x;   // channel/row (64 threads = 1 wave)
    float v = dict[c * N_ATOMS + n];
    float sq = v * v;
    #pragma unroll
    for (int off = 32; off > 0; off >>= 1) sq += __shfl_down(sq, off);
    sq = __shfl(sq, 0);
    float m = fmaxf(sqrtf(sq), 1e-10f);
    float r = v / m;             // division to match reference exactly
    Dn[c * N_ATOMS + n] = r;
    DnT[n * CDIM + c]  = r;
    if (n == 0 && c == 0) out[LOSS_IDX] = 0.f;
}

__global__ void k_gram(const float* __restrict__ Dn, float* __restrict__ G) {
    __shared__ float sc[CDIM];
    const int i = blockIdx.x;
    const int t = threadIdx.x;
    if (t < CDIM) sc[t] = Dn[t * N_ATOMS + i];
    __syncthreads();
    for (int j = t; j < N_ATOMS; j += 256) {
        float a = 0.f;
        #pragma unroll
        for (int c = 0; c < CDIM; c++) a = fmaf(sc[c], Dn[c * N_ATOMS + j], a);
        G[i * N_ATOMS + j] = a;
    }
}

// 8-way select, VALUE-passed (pointer-escape of register arrays sends them
// to scratch — round-4 lesson). e wave-uniform; 7-cndmask tree.
__device__ __forceinline__ float sel8v(float f0, float f1, float f2, float f3,
                                       float f4, float f5, float f6, float f7,
                                       int e) {
    float x0 = (e & 1) ? f1 : f0;
    float x1 = (e & 1) ? f3 : f2;
    float x2 = (e & 1) ? f5 : f4;
    float x3 = (e & 1) ? f7 : f6;
    float y0 = (e & 2) ? x1 : x0;
    float y1 = (e & 2) ? x3 : x2;
    return (e & 4) ? y1 : y0;
}
#define SEL8(arr, e) sel8v(arr[0], arr[1], arr[2], arr[3], \
                           arr[4], arr[5], arr[6], arr[7], e)

// DPP max step: v = max(v, v shifted by ctrl). bound_ctrl=1 -> OOB lanes
// contribute +0.0f, safe because all reduced values are >= 0. Pure VALU
// (~4 cy) vs ds_bpermute (~40-120 cy) per level.
#define DPPMAX(v, ctrl)                                                     \
    v = fmaxf(v, __int_as_float(__builtin_amdgcn_update_dpp(                \
            0, __float_as_int(v), (ctrl), 0xf, 0xf, true)))

// readlane broadcast of a float from a wave-uniform lane (replaces
// __shfl with uniform src: v_readlane_b32 instead of ds_bpermute).
__device__ __forceinline__ float rdlane_f(float v, int lane) {
    return __int_as_float(__builtin_amdgcn_readlane(__float_as_int(v), lane));
}

// OMP body v16 = r7's verified v11 body with the lane-local argmax as a
// left-biased tournament tree (harness-validated in r10: identical tokens).
// Left-bias on >= keeps the FIRST maximal element -> identical lowest-index
// tie-break as the sequential scan (incl. the all-zero degenerate case).
// Wave reduce (DPP), ballot+ffs lowest-lane winner, register G-rows,
// readlane extractions unchanged -> tokens/zste bit-identical.
__device__ __forceinline__ void omp_body(
    const float hb[8], const float* __restrict__ G, int lane,
    int I[KS], float coef[KS])
{
    float h[8];
    #pragma unroll
    for (int j = 0; j < 8; j++) h[j] = hb[j];

    unsigned sel = 0;
    float L[KS][KS];
    float hsel[KS];
    float inv[KS];
    float r[KS - 1][8];                 // kept G-row fragments (registers)
    L[0][0] = 1.f; inv[0] = 1.f;

    #pragma unroll
    for (int k = 0; k < KS; k++) {
        // lane-local argmax of |where(selected, 0, h)| — tournament tree,
        // left-biased (>=) == first-max == lowest-j tie-break
        float m[8];
        #pragma unroll
        for (int j = 0; j < 8; j++)
            m[j] = (sel & (1u << j)) ? 0.f : fabsf(h[j]);
        float va = (m[0] >= m[1]) ? m[0] : m[1]; int ia = (m[0] >= m[1]) ? 0 : 1;
        float vb = (m[2] >= m[3]) ? m[2] : m[3]; int ib = (m[2] >= m[3]) ? 2 : 3;
        float vc = (m[4] >= m[5]) ? m[4] : m[5]; int ic = (m[4] >= m[5]) ? 4 : 5;
        float vd = (m[6] >= m[7]) ? m[6] : m[7]; int id = (m[6] >= m[7]) ? 6 : 7;
        float ve = (va >= vb) ? va : vb;         int ie = (va >= vb) ? ia : ib;
        float vf = (vc >= vd) ? vc : vd;         int jf = (vc >= vd) ? ic : id;
        float bv = (ve >= vf) ? ve : vf;
        const int bn = lane * 8 + ((ve >= vf) ? ie : jf);
        // wave max in lane 63 via DPP (VALU-speed), then SGPR broadcast
        float wv = bv;
        DPPMAX(wv, 0x111);   // row_shr:1
        DPPMAX(wv, 0x112);   // row_shr:2
        DPPMAX(wv, 0x114);   // row_shr:4
        DPPMAX(wv, 0x118);   // row_shr:8
        DPPMAX(wv, 0x142);   // row_bcast:15
        DPPMAX(wv, 0x143);   // row_bcast:31
        const float wm = rdlane_f(wv, 63);
        const int win = (int)__ffsll(__ballot(bv == wm)) - 1; // lowest lane
        const int idx = __builtin_amdgcn_readlane(bn, win);
        if ((idx >> 3) == lane) sel |= 1u << (idx & 7);
        const int owner = idx >> 3, e = idx & 7;

        if (k < KS - 1) {   // load row I[k]=idx early; latency hides under solves
            const float4* gr = (const float4*)(G + idx * N_ATOMS + lane * 8);
            float4 g0 = gr[0], g1 = gr[1];
            r[k][0] = g0.x; r[k][1] = g0.y; r[k][2] = g0.z; r[k][3] = g0.w;
            r[k][4] = g1.x; r[k][5] = g1.y; r[k][6] = g1.z; r[k][7] = g1.w;
        }

        if (k > 0) {
            float w[KS - 1];
            #pragma unroll
            for (int i2 = 0; i2 < k; i2++) {
                float t = rdlane_f(SEL8(r[i2], e), owner);  // G[I[i2]][idx]
                #pragma unroll
                for (int j2 = 0; j2 < i2; j2++) t -= L[i2][j2] * w[j2];
                w[i2] = t * inv[i2];
            }
            float ssum = 0.f;
            #pragma unroll
            for (int j2 = 0; j2 < k; j2++) ssum += w[j2] * w[j2];
            float corner = sqrtf(fmaxf(1.f - ssum, 1e-12f));
            #pragma unroll
            for (int j2 = 0; j2 < k; j2++) L[k][j2] = w[j2];
            L[k][k] = corner;
            inv[k] = 1.f / corner;
        }
        I[k] = idx;
        hsel[k] = rdlane_f(SEL8(hb, e), owner);   // hbar[idx], same bits

        float y[KS];
        #pragma unroll
        for (int i2 = 0; i2 <= k; i2++) {
            float t = hsel[i2];
            #pragma unroll
            for (int j2 = 0; j2 < i2; j2++) t -= L[i2][j2] * y[j2];
            y[i2] = t * inv[i2];
        }
        #pragma unroll
        for (int i2 = k; i2 >= 0; i2--) {
            float t = y[i2];
            #pragma unroll
            for (int j2 = i2 + 1; j2 <= k; j2++) t -= L[j2][i2] * coef[j2];
            coef[i2] = t * inv[i2];
        }

        if (k < KS - 1) {
            float a[8];
            #pragma unroll
            for (int j = 0; j < 8; j++) a[j] = 0.f;
            #pragma unroll
            for (int m2 = 0; m2 <= k; m2++) {
                float cm = coef[m2];
                #pragma unroll
                for (int j = 0; j < 8; j++) a[j] = fmaf(cm, r[m2][j], a[j]);
            }
            #pragma unroll
            for (int j = 0; j < 8; j++) h[j] = hb[j] - a[j];
        }
    }
}

// Fused v16: r7's proven skeleton verbatim (512 thr, (512,3), 1 signal/wave,
// scalar coalesced Dn GEMM — the only shape that codegens clean: 36 VGPR,
// zero spill, 44.1 us) + tree argmax + GEMM k-loop unroll 4 (batches 4 Dn
// loads / 8 LDS reads per issue group; fmaf order unchanged).
__global__ __launch_bounds__(512, 3) void k_fused12(
    const float* __restrict__ z, const float* __restrict__ Dn,
    const float* __restrict__ DnT, const float* __restrict__ G,
    float* __restrict__ out)
{
    __shared__ float Xs[CDIM][NS_BLK];      // [c][s] 2 KB
    __shared__ float Hs[NS_BLK][516];       // hbar tile 16.5 KB; reused for zste
    __shared__ float tk[NS_BLK][4];
    __shared__ float lred[NS_BLK];
    const int t = threadIdx.x;
    const int wave = t >> 6, lane = t & 63;
    const int s0 = blockIdx.x * NS_BLK;
    const int b = s0 >> 10;
    const int hw0 = s0 & 1023;

    if (t < 128) {   // coalesced z stage: c = t>>1, signals f..f+3 (f = (t&1)*4)
        const int c = t >> 1, f = (t & 1) * 4;
        float4 v = *(const float4*)(z + (b * CDIM + c) * 1024 + hw0 + f);
        Xs[c][f + 0] = v.x; Xs[c][f + 1] = v.y;
        Xs[c][f + 2] = v.z; Xs[c][f + 3] = v.w;
    }
    __syncthreads();

    {   // GEMM: wave owns atoms [wave*64, +64); lane owns 1 atom.
        // k-ascending fmaf per (signal, atom) — bit-identical to prior rounds.
        const int n0 = wave * 64 + lane;
        float acc[NS_BLK];
        #pragma unroll
        for (int q = 0; q < NS_BLK; q++) acc[q] = 0.f;
        #pragma unroll 4
        for (int k = 0; k < CDIM; k++) {
            const float d = Dn[k * N_ATOMS + n0];
            float4 xlo = *(const float4*)(&Xs[k][0]);
            float4 xhi = *(const float4*)(&Xs[k][4]);
            const float xs[NS_BLK] = {xlo.x, xlo.y, xlo.z, xlo.w,
                                      xhi.x, xhi.y, xhi.z, xhi.w};
            #pragma unroll
            for (int q = 0; q < NS_BLK; q++)
                acc[q] = fmaf(xs[q], d, acc[q]);
        }
        #pragma unroll
        for (int q = 0; q < NS_BLK; q++) Hs[q][n0] = acc[q];
    }
    __syncthreads();

    // OMP: one signal per wave (sl = wave). 8 independent chains per block.
    {
        const int sl = wave;
        const float xch = Xs[lane][sl];

        float hb[8];
        *(float4*)(&hb[0]) = *(const float4*)(&Hs[sl][lane * 8]);
        *(float4*)(&hb[4]) = *(const float4*)(&Hs[sl][lane * 8 + 4]);

        int I[KS]; float coef[KS];
        omp_body(hb, G, lane, I, coef);

        int tok[KS]; float cq[KS];
        #pragma unroll
        for (int j = 0; j < KS; j++) {
            float c2 = fminf(fmaxf(coef[j], -2.f), 2.f);
            float bf = (c2 + 2.f) / 4.f * 32.f;
            int bin = (int)rintf(bf);
            bin = bin < 0 ? 0 : (bin > 32 ? 32 : bin);
            cq[j] = -2.f + 0.125f * (float)bin;
            tok[j] = I[j] * NBINS + bin;
        }
        float zq = 0.f;
        #pragma unroll
        for (int j = 0; j < KS; j++)
            zq = fmaf(cq[j], DnT[I[j] * CDIM + lane], zq);

        float diff = zq - xch;
        Hs[sl][lane] = xch + (zq - xch);   // zste overlay (row sl read is done)

        float sq = diff * diff;
        #pragma unroll
        for (int off = 32; off > 0; off >>= 1) sq += __shfl_down(sq, off);
        if (lane == 0) lred[sl] = sq;
        if (lane < KS) tk[sl][lane] = (float)tok[lane];
    }
    __syncthreads();

    if (t < 128) {   // coalesced zste write: c = t>>1, signals f..f+3
        const int c = t >> 1, f = (t & 1) * 4;
        float4 v;
        v.x = Hs[f + 0][c]; v.y = Hs[f + 1][c];
        v.z = Hs[f + 2][c]; v.w = Hs[f + 3][c];
        *(float4*)(out + (b * CDIM + c) * 1024 + hw0 + f) = v;
    }
    if (t < NS_BLK * KS)   // 32 consecutive token floats
        out[NSIG * CDIM + 1 + s0 * KS + t] = tk[t >> 2][t & 3];
    if (t == 0) {          // one pre-scaled atomic per block; 1.25/2^20 exact
        float bl = 0.f;
        #pragma unroll
        for (int q = 0; q < NS_BLK; q++) bl += lred[q];
        atomicAdd(out + LOSS_IDX, bl * (1.25f / 1048576.f));
    }
}

extern "C" void kernel_launch(void* const* d_in, const int* in_sizes, int n_in,
                              void* d_out, int out_size, void* d_ws, size_t ws_size,
                              hipStream_t stream) {
    const float* z    = (const float*)d_in[0];
    const float* dict = (const float*)d_in[1];
    float* out  = (float*)d_out;
    float* w    = (float*)d_ws;
    float* Dn   = w + WS_DN;
    float* DnT  = w + WS_DNT;
    float* G    = w + WS_G;

    hipLaunchKernelGGL(k_normalize, dim3(N_ATOMS), dim3(CDIM), 0, stream,
                       dict, Dn, DnT, out);
    hipLaunchKernelGGL(k_gram,      dim3(N_ATOMS), dim3(256),  0, stream, Dn, G);
    hipLaunchKernelGGL(k_fused12,   dim3(NSIG / NS_BLK), dim3(512), 0, stream,
                       z, Dn, DnT, G, out);
}

// Round 12
// 101.202 us; speedup vs baseline: 1.3576x; 1.1372x over previous
//
#include <hip/hip_runtime.h>
#include <hip/hip_bf16.h>

#define N_ATOMS 512
#define CDIM 64
#define NSIG 16384
#define KS 4
#define NBINS 33
#define NS_BLK 8    // signals per fused block (8 waves; wave = 64 atoms in GEMM, 1 signal in OMP)

// ws layout (floats): [0,32768) Dn[c][n] ; [32768,65536) DnT[n][c] ;
// [65536,327680) G[n][n]
#define WS_DN   0
#define WS_DNT  32768
#define WS_G    65536
#define LOSS_IDX (NSIG * CDIM)

// k_normalize also zero-inits the loss slot for the fused kernel's atomics.
__global__ void k_normalize(const float* __restrict__ dict,
                            float* __restrict__ Dn, float* __restrict__ DnT,
                            float* __restrict__ out) {
    const int n = blockIdx.x;    // atom/column
    const int c = threadIdx.x;   // channel/row (64 threads = 1 wave)
    float v = dict[c * N_ATOMS + n];
    float sq = v * v;
    #pragma unroll
    for (int off = 32; off > 0; off >>= 1) sq += __shfl_down(sq, off);
    sq = __shfl(sq, 0);
    float m = fmaxf(sqrtf(sq), 1e-10f);
    float r = v / m;             // division to match reference exactly
    Dn[c * N_ATOMS + n] = r;
    DnT[n * CDIM + c]  = r;
    if (n == 0 && c == 0) out[LOSS_IDX] = 0.f;
}

// 512 threads: one j per thread (was 2 at 256 thr). Per-(i,j) fmaf chain
// over sc unchanged -> G bit-identical; one fewer loop trip in a hot-ish
// prep kernel. Fused kernel below is r7's verified bytes, untouched.
__global__ void k_gram(const float* __restrict__ Dn, float* __restrict__ G) {
    __shared__ float sc[CDIM];
    const int i = blockIdx.x;
    const int t = threadIdx.x;
    if (t < CDIM) sc[t] = Dn[t * N_ATOMS + i];
    __syncthreads();
    for (int j = t; j < N_ATOMS; j += 512) {
        float a = 0.f;
        #pragma unroll
        for (int c = 0; c < CDIM; c++) a = fmaf(sc[c], Dn[c * N_ATOMS + j], a);
        G[i * N_ATOMS + j] = a;
    }
}

// 8-way select, VALUE-passed (pointer-escape of register arrays sends them
// to scratch — round-4 lesson). e wave-uniform; 7-cndmask tree.
__device__ __forceinline__ float sel8v(float f0, float f1, float f2, float f3,
                                       float f4, float f5, float f6, float f7,
                                       int e) {
    float x0 = (e & 1) ? f1 : f0;
    float x1 = (e & 1) ? f3 : f2;
    float x2 = (e & 1) ? f5 : f4;
    float x3 = (e & 1) ? f7 : f6;
    float y0 = (e & 2) ? x1 : x0;
    float y1 = (e & 2) ? x3 : x2;
    return (e & 4) ? y1 : y0;
}
#define SEL8(arr, e) sel8v(arr[0], arr[1], arr[2], arr[3], \
                           arr[4], arr[5], arr[6], arr[7], e)

// DPP max step: v = max(v, v shifted by ctrl). bound_ctrl=1 -> OOB lanes
// contribute +0.0f, safe because all reduced values are >= 0. Pure VALU
// (~4 cy) vs ds_bpermute (~40-120 cy) per level.
#define DPPMAX(v, ctrl)                                                     \
    v = fmaxf(v, __int_as_float(__builtin_amdgcn_update_dpp(                \
            0, __float_as_int(v), (ctrl), 0xf, 0xf, true)))

// readlane broadcast of a float from a wave-uniform lane (replaces
// __shfl with uniform src: v_readlane_b32 instead of ds_bpermute).
__device__ __forceinline__ float rdlane_f(float v, int lane) {
    return __int_as_float(__builtin_amdgcn_readlane(__float_as_int(v), lane));
}

// OMP body v11 — r7's verified bytes (36 VGPR / zero spill / 44.1 us):
// sequential-scan lane argmax (r11 showed the "faster" tree+unroll variant
// regressed 25%), DPP row_shr/row_bcast wave max (exact fmaxf), ballot+ffs
// lowest-lane winner (= lowest atom index tie-break), register-kept G rows,
// readlane extractions. Tokens/zste bit-identical to all passing rounds.
__device__ __forceinline__ void omp_body(
    const float hb[8], const float* __restrict__ G, int lane,
    int I[KS], float coef[KS])
{
    float h[8];
    #pragma unroll
    for (int j = 0; j < 8; j++) h[j] = hb[j];

    unsigned sel = 0;
    float L[KS][KS];
    float hsel[KS];
    float inv[KS];
    float r[KS - 1][8];                 // kept G-row fragments (registers)
    L[0][0] = 1.f; inv[0] = 1.f;

    #pragma unroll
    for (int k = 0; k < KS; k++) {
        // lane-local argmax of |where(selected, 0, h)|, lowest-j tie-break
        float bv = -1.f; int bn = N_ATOMS;
        #pragma unroll
        for (int j = 0; j < 8; j++) {
            float v = (sel & (1u << j)) ? 0.f : fabsf(h[j]);
            if (v > bv) { bv = v; bn = lane * 8 + j; }
        }
        // wave max in lane 63 via DPP (VALU-speed), then SGPR broadcast
        float wv = bv;
        DPPMAX(wv, 0x111);   // row_shr:1
        DPPMAX(wv, 0x112);   // row_shr:2
        DPPMAX(wv, 0x114);   // row_shr:4
        DPPMAX(wv, 0x118);   // row_shr:8
        DPPMAX(wv, 0x142);   // row_bcast:15
        DPPMAX(wv, 0x143);   // row_bcast:31
        const float wm = rdlane_f(wv, 63);
        const int win = (int)__ffsll(__ballot(bv == wm)) - 1; // lowest lane
        const int idx = __builtin_amdgcn_readlane(bn, win);
        if ((idx >> 3) == lane) sel |= 1u << (idx & 7);
        const int owner = idx >> 3, e = idx & 7;

        if (k < KS - 1) {   // load row I[k]=idx early; latency hides under solves
            const float4* gr = (const float4*)(G + idx * N_ATOMS + lane * 8);
            float4 g0 = gr[0], g1 = gr[1];
            r[k][0] = g0.x; r[k][1] = g0.y; r[k][2] = g0.z; r[k][3] = g0.w;
            r[k][4] = g1.x; r[k][5] = g1.y; r[k][6] = g1.z; r[k][7] = g1.w;
        }

        if (k > 0) {
            float w[KS - 1];
            #pragma unroll
            for (int i2 = 0; i2 < k; i2++) {
                float t = rdlane_f(SEL8(r[i2], e), owner);  // G[I[i2]][idx]
                #pragma unroll
                for (int j2 = 0; j2 < i2; j2++) t -= L[i2][j2] * w[j2];
                w[i2] = t * inv[i2];
            }
            float ssum = 0.f;
            #pragma unroll
            for (int j2 = 0; j2 < k; j2++) ssum += w[j2] * w[j2];
            float corner = sqrtf(fmaxf(1.f - ssum, 1e-12f));
            #pragma unroll
            for (int j2 = 0; j2 < k; j2++) L[k][j2] = w[j2];
            L[k][k] = corner;
            inv[k] = 1.f / corner;
        }
        I[k] = idx;
        hsel[k] = rdlane_f(SEL8(hb, e), owner);   // hbar[idx], same bits

        float y[KS];
        #pragma unroll
        for (int i2 = 0; i2 <= k; i2++) {
            float t = hsel[i2];
            #pragma unroll
            for (int j2 = 0; j2 < i2; j2++) t -= L[i2][j2] * y[j2];
            y[i2] = t * inv[i2];
        }
        #pragma unroll
        for (int i2 = k; i2 >= 0; i2--) {
            float t = y[i2];
            #pragma unroll
            for (int j2 = i2 + 1; j2 <= k; j2++) t -= L[j2][i2] * coef[j2];
            coef[i2] = t * inv[i2];
        }

        if (k < KS - 1) {
            float a[8];
            #pragma unroll
            for (int j = 0; j < 8; j++) a[j] = 0.f;
            #pragma unroll
            for (int m = 0; m <= k; m++) {
                float cm = coef[m];
                #pragma unroll
                for (int j = 0; j < 8; j++) a[j] = fmaf(cm, r[m][j], a[j]);
            }
            #pragma unroll
            for (int j = 0; j < 8; j++) h[j] = hb[j] - a[j];
        }
    }
}

// Fused v11 (r7 verbatim): 512 thr, (512,3), 1 signal/wave, scalar coalesced
// Dn GEMM. The only shape that codegens clean (36 VGPR, zero spill) at the
// session-best 44.1 us. All r9-r11 deviations regressed; this is the bank.
__global__ __launch_bounds__(512, 3) void k_fused8(
    const float* __restrict__ z, const float* __restrict__ Dn,
    const float* __restrict__ DnT, const float* __restrict__ G,
    float* __restrict__ out)
{
    __shared__ float Xs[CDIM][NS_BLK];      // [c][s] 2 KB
    __shared__ float Hs[NS_BLK][516];       // hbar tile 16.5 KB; reused for zste
    __shared__ float tk[NS_BLK][4];
    __shared__ float lred[NS_BLK];
    const int t = threadIdx.x;
    const int wave = t >> 6, lane = t & 63;
    const int s0 = blockIdx.x * NS_BLK;
    const int b = s0 >> 10;
    const int hw0 = s0 & 1023;

    if (t < 128) {   // coalesced z stage: c = t>>1, signals f..f+3 (f = (t&1)*4)
        const int c = t >> 1, f = (t & 1) * 4;
        float4 v = *(const float4*)(z + (b * CDIM + c) * 1024 + hw0 + f);
        Xs[c][f + 0] = v.x; Xs[c][f + 1] = v.y;
        Xs[c][f + 2] = v.z; Xs[c][f + 3] = v.w;
    }
    __syncthreads();

    {   // GEMM: wave owns atoms [wave*64, +64); lane owns 1 atom.
        // k-ascending fmaf per (signal, atom) — bit-identical to prior rounds.
        const int n0 = wave * 64 + lane;
        float acc[NS_BLK];
        #pragma unroll
        for (int q = 0; q < NS_BLK; q++) acc[q] = 0.f;
        for (int k = 0; k < CDIM; k++) {
            const float d = Dn[k * N_ATOMS + n0];
            float4 xlo = *(const float4*)(&Xs[k][0]);
            float4 xhi = *(const float4*)(&Xs[k][4]);
            const float xs[NS_BLK] = {xlo.x, xlo.y, xlo.z, xlo.w,
                                      xhi.x, xhi.y, xhi.z, xhi.w};
            #pragma unroll
            for (int q = 0; q < NS_BLK; q++)
                acc[q] = fmaf(xs[q], d, acc[q]);
        }
        #pragma unroll
        for (int q = 0; q < NS_BLK; q++) Hs[q][n0] = acc[q];
    }
    __syncthreads();

    // OMP: one signal per wave (sl = wave). 8 independent chains per block.
    {
        const int sl = wave;
        const float xch = Xs[lane][sl];

        float hb[8];
        *(float4*)(&hb[0]) = *(const float4*)(&Hs[sl][lane * 8]);
        *(float4*)(&hb[4]) = *(const float4*)(&Hs[sl][lane * 8 + 4]);

        int I[KS]; float coef[KS];
        omp_body(hb, G, lane, I, coef);

        int tok[KS]; float cq[KS];
        #pragma unroll
        for (int j = 0; j < KS; j++) {
            float c2 = fminf(fmaxf(coef[j], -2.f), 2.f);
            float bf = (c2 + 2.f) / 4.f * 32.f;
            int bin = (int)rintf(bf);
            bin = bin < 0 ? 0 : (bin > 32 ? 32 : bin);
            cq[j] = -2.f + 0.125f * (float)bin;
            tok[j] = I[j] * NBINS + bin;
        }
        float zq = 0.f;
        #pragma unroll
        for (int j = 0; j < KS; j++)
            zq = fmaf(cq[j], DnT[I[j] * CDIM + lane], zq);

        float diff = zq - xch;
        Hs[sl][lane] = xch + (zq - xch);   // zste overlay (row sl read is done)

        float sq = diff * diff;
        #pragma unroll
        for (int off = 32; off > 0; off >>= 1) sq += __shfl_down(sq, off);
        if (lane == 0) lred[sl] = sq;
        if (lane < KS) tk[sl][lane] = (float)tok[lane];
    }
    __syncthreads();

    if (t < 128) {   // coalesced zste write: c = t>>1, signals f..f+3
        const int c = t >> 1, f = (t & 1) * 4;
        float4 v;
        v.x = Hs[f + 0][c]; v.y = Hs[f + 1][c];
        v.z = Hs[f + 2][c]; v.w = Hs[f + 3][c];
        *(float4*)(out + (b * CDIM + c) * 1024 + hw0 + f) = v;
    }
    if (t < NS_BLK * KS)   // 32 consecutive token floats
        out[NSIG * CDIM + 1 + s0 * KS + t] = tk[t >> 2][t & 3];
    if (t == 0) {          // one pre-scaled atomic per block; 1.25/2^20 exact
        float bl = 0.f;
        #pragma unroll
        for (int q = 0; q < NS_BLK; q++) bl += lred[q];
        atomicAdd(out + LOSS_IDX, bl * (1.25f / 1048576.f));
    }
}

extern "C" void kernel_launch(void* const* d_in, const int* in_sizes, int n_in,
                              void* d_out, int out_size, void* d_ws, size_t ws_size,
                              hipStream_t stream) {
    const float* z    = (const float*)d_in[0];
    const float* dict = (const float*)d_in[1];
    float* out  = (float*)d_out;
    float* w    = (float*)d_ws;
    float* Dn   = w + WS_DN;
    float* DnT  = w + WS_DNT;
    float* G    = w + WS_G;

    hipLaunchKernelGGL(k_normalize, dim3(N_ATOMS), dim3(CDIM), 0, stream,
                       dict, Dn, DnT, out);
    hipLaunchKernelGGL(k_gram,      dim3(N_ATOMS), dim3(512),  0, stream, Dn, G);
    hipLaunchKernelGGL(k_fused8,    dim3(NSIG / NS_BLK), dim3(512), 0, stream,
                       z, Dn, DnT, G, out);
}